// Round 7
// baseline (1015.795 us; speedup 1.0000x reference)
//
#include <hip/hip_runtime.h>
#include <stdint.h>

// ---------------------------------------------------------------------------
// Fused 4-layer mini-BERT (B=32768, SEQ=4, D=128, H=4, DH=64) for gfx950.
// Round 11: occupancy push on the PASSING round-10 base (628us, absmax
// 0.0156). Arithmetic byte-identical (hand-RNE packs, post-add biases,
// V-in-registers). Structural only:
//   - h1 relocated to Q region (V region deleted) -> PG 8960
//   - single 16KB weight slot, reg-prefetch + ds_write commit,
//     two barriers/phase (round-7 schedule, now without the poisoned pack)
//   - LDS 78848 -> 52224 B => 3 WGs/CU (12 waves/CU, was 8)
// Rounds 5-7 never falsified this structure: their NaN/0.16 came from the
// asm pack (1) and bias-seed (2), both reverted here.
// ---------------------------------------------------------------------------

typedef __attribute__((ext_vector_type(8))) short    bf16x8;  // 8 bf16
typedef __attribute__((ext_vector_type(4))) _Float16 f16x4;
typedef __attribute__((ext_vector_type(4))) float    f32x4;

#define MFMA_BF(a,b,c) __builtin_amdgcn_mfma_f32_16x16x32_bf16((a),(b),(c),0,0,0)
#define MFMA_H(a,b,c)  __builtin_amdgcn_mfma_f32_16x16x16f16((a),(b),(c),0,0,0)

__device__ __forceinline__ unsigned short f2bf(float f){
  unsigned u = __float_as_uint(f);
  u += 0x7FFFu + ((u>>16)&1u);          // RNE
  return (unsigned short)(u>>16);
}
__device__ __forceinline__ unsigned pk2bf(float a, float b){
  return (unsigned)f2bf(a) | ((unsigned)f2bf(b)<<16);
}
__device__ __forceinline__ unsigned pkh(float a, float b){
  auto h = __builtin_amdgcn_cvt_pkrtz(a, b);    // v_cvt_pkrtz_f16_f32
  return __builtin_bit_cast(unsigned, h);
}
__device__ __forceinline__ void ubf2(unsigned u, float& a, float& b){
  a = __uint_as_float(u<<16);
  b = __uint_as_float(u & 0xffff0000u);
}

// ---------------- ws layout: 72 tiles of 8192 bf16 (16 KB), stage order -----
// tile t = l*18 + r;  r = h*4 + {0:wq,1:wk,2:wv,3:wo}, r=16:w1, r=17:w2.
// Each tile: 16 chunks of 512 elems; chunk c, lane, j ->
//   qkv/w1 (A/B-frag, m/n = f): f=(c>>2)*16+lnid, k=d=(c&3)*32+qid*8+j
//   wo/w2  (A-frag,   m = d) : d=(c>>1)*16+lnid, k=(c&1)*32+qid*8+j
__global__ __launch_bounds__(256) void prep_kernel(
    const float* __restrict__ wq, const float* __restrict__ wk,
    const float* __restrict__ wv, const float* __restrict__ wo,
    const float* __restrict__ w1, const float* __restrict__ w2,
    unsigned short* __restrict__ ws){
  int e16 = blockIdx.x*256 + threadIdx.x;       // 0..73727 (one uint4 each)
  int t    = e16 >> 10;
  int c    = (e16 >> 6) & 15;
  int lane = e16 & 63;
  int lnid = lane & 15, qid = lane >> 4;
  int l = t/18, r = t - l*18;
  float v[8];
  if (r < 16){
    int h = r >> 2, ty = r & 3;
    if (ty < 3){
      const float* W = (ty==0? wq : (ty==1? wk : wv)) + (size_t)(l*4+h)*8192;
      int f = (c>>2)*16 + lnid, d0 = (c&3)*32 + qid*8;
      #pragma unroll
      for (int j=0;j<8;++j) v[j] = W[(d0+j)*64 + f];
    } else {
      const float* W = wo + (size_t)l*32768 + (size_t)h*8192;  // rows h*64..
      int dd = (c>>1)*16 + lnid, k0 = (c&1)*32 + qid*8;
      #pragma unroll
      for (int j=0;j<8;++j) v[j] = W[(k0+j)*128 + dd];
    }
  } else if (r == 16){
    const float* W = w1 + (size_t)l*8192;
    int f = (c>>2)*16 + lnid, d0 = (c&3)*32 + qid*8;
    #pragma unroll
    for (int j=0;j<8;++j) v[j] = W[(d0+j)*64 + f];
  } else {
    const float* W = w2 + (size_t)l*8192;
    int dd = (c>>1)*16 + lnid, k0 = (c&1)*32 + qid*8;
    #pragma unroll
    for (int j=0;j<8;++j) v[j] = W[(k0+j)*128 + dd];
  }
  uint4 o;
  o.x = pk2bf(v[0],v[1]); o.y = pk2bf(v[2],v[3]);
  o.z = pk2bf(v[4],v[5]); o.w = pk2bf(v[6],v[7]);
  ((uint4*)ws)[e16] = o;
}

// ---------------- LDS layout (per group of 16 rows, stride PG) --------------
//  XOFF: X residual  bf16 [16][pitch 136]           4352 B (live whole layer)
//  QOFF: Q / ctx / h1 [16][pitch 144]               2304 B (max used 2288)
//  KOFF: K [16][pitch 144]                          2304 B (max used 2288)
//  X2 [16][pitch 136] written at QOFF spans QOFF..QOFF+4336 (K dead then).
//  Single weight slot at WSOFF (16 KB), reg-prefetch + ds_write commit.
#define XOFF  0
#define QOFF  4352
#define KOFF  6656
#define PG    8960
#define WSOFF 35840
#define SLOTSZ 16384
#define LDSSZ 52224

__global__ __launch_bounds__(256,3) void bert_kernel(
    const float* __restrict__ emb,
    const float* __restrict__ bq, const float* __restrict__ bk, const float* __restrict__ bv,
    const float* __restrict__ bo,
    const float* __restrict__ ln1g, const float* __restrict__ ln1b,
    const float* __restrict__ fb1, const float* __restrict__ fb2,
    const float* __restrict__ ln2g, const float* __restrict__ ln2b,
    const unsigned short* __restrict__ ws,
    float* __restrict__ out)
{
  __shared__ __align__(16) char smem[LDSSZ];
  const int tid  = threadIdx.x;
  const int wid  = tid>>6;
  const int lane = tid&63;
  const int lnid = lane&15;
  const int qid  = lane>>4;
  const int batch0 = blockIdx.x*16;
  char* gb = smem + wid*PG;
  char* slot = smem + WSOFF;
  const f32x4 ZV = {0.f,0.f,0.f,0.f};
  const uint4* wsv = (const uint4*)ws;

  // ---- initial X: embeddings[:, :4, :] -> bf16 LDS row-major [16][136] ----
  {
    int row = lane>>2, colq = (lane&3)*32;
    const float* src = emb + ((size_t)(batch0 + wid*4 + (row>>2))*6 + (row&3))*128 + colq;
    #pragma unroll
    for (int i=0;i<8;++i){
      float4 v = *(const float4*)(src + i*4);
      uint2 u; u.x = pk2bf(v.x,v.y); u.y = pk2bf(v.z,v.w);
      *(uint2*)(gb + XOFF + row*272 + (colq+i*4)*2) = u;
    }
  }
  // ---- passthrough: rows 4 (positive) and 5 (negatives) ----
  {
    const float* eb = emb + (size_t)batch0*768;
    float* o1 = out + 4194304 + (size_t)batch0*128;
    float* o2 = out + 8388608 + (size_t)batch0*128;
    #pragma unroll
    for (int i=0;i<4;++i){
      int idx = i*256 + tid;           // 0..1023 float4s
      int b = idx>>6, rem = idx&63;
      float4 v = *(const float4*)(eb + b*768 + 512 + rem*4);
      if (rem<32) *(float4*)(o1 + b*128 + rem*4) = v;
      else        *(float4*)(o2 + b*128 + (rem-32)*4) = v;
    }
  }
  // ---- stage tile 0 into the slot ----
  {
    #pragma unroll
    for (int i=0;i<4;++i)
      *(uint4*)(slot + (i*256+tid)*16) = wsv[i*256+tid];
  }
  __syncthreads();

  f32x4  pacc[8];
  bf16x8 xfrag[4];
  f16x4  vreg[4];

  for (int l=0; l<4; ++l){
    #pragma unroll
    for (int kc=0;kc<4;++kc)
      xfrag[kc] = *(const bf16x8*)(gb + XOFF + lnid*272 + kc*64 + qid*16);
    #pragma unroll
    for (int nt=0;nt<8;++nt) pacc[nt] = ZV;

    for (int ph=0; ph<18; ++ph){
      const int nxt = l*18 + ph + 1;
      const bool havepf = (nxt < 72);
      uint4 pf0, pf1, pf2, pf3;
      if (havepf){                       // prefetch next tile -> regs
        const uint4* p = wsv + (size_t)nxt*1024 + tid;
        pf0 = p[0]; pf1 = p[256]; pf2 = p[512]; pf3 = p[768];
      }
      auto commit = [&](){               // ds_write next tile (between barriers)
        if (havepf){
          uint4* q = (uint4*)slot + tid;
          q[0]=pf0; q[256]=pf1; q[512]=pf2; q[768]=pf3;
        }
      };

      if (ph < 16){
        int h = ph>>2, t = ph&3;
        if (t < 2){
          // ---- Q^T / K^T = W^T · X^T : A = W-frag, B = X-frag ----
          const float* bias_base = (t? bk : bq) + (l*4+h)*64;
          f32x4 a4[4];
          #pragma unroll
          for (int nt=0; nt<4; ++nt){
            f32x4 a = ZV;
            #pragma unroll
            for (int kc=0; kc<4; ++kc){
              bf16x8 wf = *(const bf16x8*)(slot + (nt*4+kc)*1024 + lane*16);
              a = MFMA_BF(wf, xfrag[kc], a);
            }
            a4[nt] = a;
          }
          __syncthreads();               // all waves done reading slot
          commit();
          char* dst = gb + (t? KOFF : QOFF);
          #pragma unroll
          for (int nt=0; nt<4; ++nt){
            f32x4 bs = *(const f32x4*)(bias_base + nt*16 + qid*4);
            uint2 u; u.x = pk2bf(a4[nt][0]+bs[0], a4[nt][1]+bs[1]);
                     u.y = pk2bf(a4[nt][2]+bs[2], a4[nt][3]+bs[3]);
            *(uint2*)(dst + lnid*144 + nt*32 + qid*8) = u;   // [s][f] row-major
          }
          __syncthreads();               // slot now holds next tile
        } else if (t == 2){
          // ---- V = X · Wv (unflipped): C regs -> vreg (round-10 proven) ----
          const float* bias_base = bv + (l*4+h)*64;
          f32x4 a4[4];
          #pragma unroll
          for (int nt=0; nt<4; ++nt){
            f32x4 a = ZV;
            #pragma unroll
            for (int kc=0; kc<4; ++kc){
              bf16x8 wf = *(const bf16x8*)(slot + (nt*4+kc)*1024 + lane*16);
              a = MFMA_BF(xfrag[kc], wf, a);
            }
            a4[nt] = a;
          }
          __syncthreads();
          commit();
          #pragma unroll
          for (int nt=0; nt<4; ++nt){
            float b = bias_base[nt*16 + lnid];
            union { unsigned u[2]; f16x4 h4; } pu;
            pu.u[0] = pkh(a4[nt][0]+b, a4[nt][1]+b);
            pu.u[1] = pkh(a4[nt][2]+b, a4[nt][3]+b);
            vreg[nt] = pu.h4;            // V^T fragment, consumed next phase
          }
          __syncthreads();
        } else {
          // ---- attention + proj partial (slot = wo tile for head h) ----
          bf16x8 kf0 = *(const bf16x8*)(gb+KOFF + lnid*144 + qid*16);
          bf16x8 kf1 = *(const bf16x8*)(gb+KOFF + lnid*144 + 64 + qid*16);
          bf16x8 qf0 = *(const bf16x8*)(gb+QOFF + lnid*144 + qid*16);
          bf16x8 qf1 = *(const bf16x8*)(gb+QOFF + lnid*144 + 64 + qid*16);
          // S^T[t][s] = K·Q^T : lane (col s=lnid) holds t = qid*4+r
          f32x4 st = MFMA_BF(kf0, qf0, ZV);
          st = MFMA_BF(kf1, qf1, st);
          float s0=st[0]*0.5f, s1=st[1]*0.5f, s2=st[2]*0.5f, s3=st[3]*0.5f;
          float mx = fmaxf(fmaxf(s0,s1), fmaxf(s2,s3));
          float p0=__expf(s0-mx), p1=__expf(s1-mx), p2=__expf(s2-mx), p3=__expf(s3-mx);
          float inv = 1.f/(p0+p1+p2+p3);
          bool valid = (lnid>>2) == qid;          // block-diagonal (4-batch tile)
          p0 = valid? p0*inv:0.f; p1 = valid? p1*inv:0.f;
          p2 = valid? p2*inv:0.f; p3 = valid? p3*inv:0.f;
          union { unsigned u[2]; f16x4 h4; } pu;
          pu.u[0] = pkh(p0,p1);
          pu.u[1] = pkh(p2,p3);
          f16x4 pf = pu.h4;                        // B-frag of 16x16x16 f16
          #pragma unroll
          for (int ft=0; ft<4; ++ft){
            f32x4 c = MFMA_H(vreg[ft], pf, ZV);    // ctx^T[f][s]
            uint2 u; u.x = pk2bf(c[0],c[1]); u.y = pk2bf(c[2],c[3]);
            *(uint2*)(gb+QOFF + lnid*144 + ft*32 + qid*8) = u;  // ctx[s][f] over Q
          }
          asm volatile("" ::: "memory");
          bf16x8 c0 = *(const bf16x8*)(gb+QOFF + lnid*144 + qid*16);
          bf16x8 c1 = *(const bf16x8*)(gb+QOFF + lnid*144 + 64 + qid*16);
          #pragma unroll
          for (int nt=0; nt<8; ++nt){
            bf16x8 w0 = *(const bf16x8*)(slot + (nt*2+0)*1024 + lane*16);
            bf16x8 w1f= *(const bf16x8*)(slot + (nt*2+1)*1024 + lane*16);
            f32x4 a = pacc[nt];
            a = MFMA_BF(w0, c0, a);
            a = MFMA_BF(w1f, c1, a);
            pacc[nt] = a;                           // proj^T: (s=lnid, d regs)
          }
          __syncthreads();
          commit();
          __syncthreads();
        }
      } else if (ph == 16){
        // ---- +bo +residual, LN1, FF1 (slot = w1); GELU+h1 after barrier ----
        float sm=0.f, sq=0.f;
        #pragma unroll
        for (int nt=0;nt<8;++nt){
          f32x4 b4 = *(const f32x4*)(bo + l*128 + nt*16 + qid*4);
          uint2 xr = *(const uint2*)(gb+XOFF + lnid*272 + nt*32 + qid*8);
          float x0,x1,x2,x3; ubf2(xr.x,x0,x1); ubf2(xr.y,x2,x3);
          f32x4 a = pacc[nt];
          a[0]+=b4[0]+x0; a[1]+=b4[1]+x1; a[2]+=b4[2]+x2; a[3]+=b4[3]+x3;
          sm += a[0]+a[1]+a[2]+a[3];
          sq += a[0]*a[0]+a[1]*a[1]+a[2]*a[2]+a[3]*a[3];
          pacc[nt] = a;
        }
        sm += __shfl_xor(sm,16); sq += __shfl_xor(sq,16);
        sm += __shfl_xor(sm,32); sq += __shfl_xor(sq,32);
        float mu = sm*(1.f/128.f);
        float rs = rsqrtf(sq*(1.f/128.f) - mu*mu + 1e-5f);
        #pragma unroll
        for (int nt=0;nt<8;++nt){
          f32x4 g4 = *(const f32x4*)(ln1g + l*128 + nt*16 + qid*4);
          f32x4 be = *(const f32x4*)(ln1b + l*128 + nt*16 + qid*4);
          f32x4 a = pacc[nt];
          float v0 = (a[0]-mu)*rs*g4[0]+be[0];
          float v1 = (a[1]-mu)*rs*g4[1]+be[1];
          float v2 = (a[2]-mu)*rs*g4[2]+be[2];
          float v3 = (a[3]-mu)*rs*g4[3]+be[3];
          uint2 u; u.x = pk2bf(v0,v1); u.y = pk2bf(v2,v3);
          *(uint2*)(gb+QOFF + lnid*272 + nt*32 + qid*8) = u;   // X2 [16][136]
        }
        asm volatile("" ::: "memory");
        bf16x8 x2f[4];
        #pragma unroll
        for (int kc=0;kc<4;++kc)
          x2f[kc] = *(const bf16x8*)(gb+QOFF + lnid*272 + kc*64 + qid*16);
        f32x4 f14[4];
        #pragma unroll
        for (int nt=0; nt<4; ++nt){
          f32x4 a = ZV;
          #pragma unroll
          for (int kc=0; kc<4; ++kc){
            bf16x8 wf = *(const bf16x8*)(slot + (nt*4+kc)*1024 + lane*16);
            a = MFMA_BF(wf, x2f[kc], a);
          }
          f14[nt] = a;
        }
        __syncthreads();
        commit();
        #pragma unroll
        for (int nt=0; nt<4; ++nt){
          f32x4 b1 = *(const f32x4*)(fb1 + l*64 + nt*16 + qid*4);
          f32x4 a = f14[nt];
          float g0,g1,g2,g3;
          { float x = a[0]+b1[0]; g0 = 0.5f*x*(1.f+erff(x*0.70710678f)); }
          { float x = a[1]+b1[1]; g1 = 0.5f*x*(1.f+erff(x*0.70710678f)); }
          { float x = a[2]+b1[2]; g2 = 0.5f*x*(1.f+erff(x*0.70710678f)); }
          { float x = a[3]+b1[3]; g3 = 0.5f*x*(1.f+erff(x*0.70710678f)); }
          uint2 u; u.x = pk2bf(g0,g1); u.y = pk2bf(g2,g3);
          *(uint2*)(gb+QOFF + lnid*144 + nt*32 + qid*8) = u;   // h1 [16][72]
        }
        __syncthreads();
      } else {
        // ---- FF2 (slot = w2); residual + LN2 -> new X after barrier ----
        bf16x8 h0  = *(const bf16x8*)(gb+QOFF + lnid*144 + qid*16);
        bf16x8 h1f = *(const bf16x8*)(gb+QOFF + lnid*144 + 64 + qid*16);
        f32x4 racc[8];
        #pragma unroll
        for (int nt=0; nt<8; ++nt){
          bf16x8 w0 = *(const bf16x8*)(slot + (nt*2+0)*1024 + lane*16);
          bf16x8 w1f= *(const bf16x8*)(slot + (nt*2+1)*1024 + lane*16);
          f32x4 a = MFMA_BF(w0, h0, ZV);
          a = MFMA_BF(w1f, h1f, a);
          racc[nt] = a;
        }
        __syncthreads();
        commit();
        float sm=0.f, sq=0.f;
        #pragma unroll
        for (int nt=0;nt<8;++nt){
          f32x4 b4 = *(const f32x4*)(fb2 + l*128 + nt*16 + qid*4);
          uint2 xr = *(const uint2*)(gb+XOFF + lnid*272 + nt*32 + qid*8);
          float x0,x1,x2,x3; ubf2(xr.x,x0,x1); ubf2(xr.y,x2,x3);
          f32x4 a = racc[nt];
          a[0]+=b4[0]+x0; a[1]+=b4[1]+x1; a[2]+=b4[2]+x2; a[3]+=b4[3]+x3;
          sm += a[0]+a[1]+a[2]+a[3];
          sq += a[0]*a[0]+a[1]*a[1]+a[2]*a[2]+a[3]*a[3];
          racc[nt] = a;
        }
        sm += __shfl_xor(sm,16); sq += __shfl_xor(sq,16);
        sm += __shfl_xor(sm,32); sq += __shfl_xor(sq,32);
        float mu = sm*(1.f/128.f);
        float rs = rsqrtf(sq*(1.f/128.f) - mu*mu + 1e-5f);
        #pragma unroll
        for (int nt=0;nt<8;++nt){
          f32x4 g4 = *(const f32x4*)(ln2g + l*128 + nt*16 + qid*4);
          f32x4 be = *(const f32x4*)(ln2b + l*128 + nt*16 + qid*4);
          f32x4 a = racc[nt];
          float v0 = (a[0]-mu)*rs*g4[0]+be[0];
          float v1 = (a[1]-mu)*rs*g4[1]+be[1];
          float v2 = (a[2]-mu)*rs*g4[2]+be[2];
          float v3 = (a[3]-mu)*rs*g4[3]+be[3];
          uint2 u; u.x = pk2bf(v0,v1); u.y = pk2bf(v2,v3);
          *(uint2*)(gb+XOFF + lnid*272 + nt*32 + qid*8) = u;   // new X
        }
        __syncthreads();
      }
    }
  }

  // ---- epilogue: final_embedding = mean over 4 seq rows ----
  {
    int bl = lane>>4;                 // batch within group
    float acc[8] = {0,0,0,0,0,0,0,0};
    #pragma unroll
    for (int s=0;s<4;++s){
      uint4 u = *(const uint4*)(gb + XOFF + (bl*4+s)*272 + lnid*16);
      float a0,a1;
      ubf2(u.x,a0,a1); acc[0]+=a0; acc[1]+=a1;
      ubf2(u.y,a0,a1); acc[2]+=a0; acc[3]+=a1;
      ubf2(u.z,a0,a1); acc[4]+=a0; acc[5]+=a1;
      ubf2(u.w,a0,a1); acc[6]+=a0; acc[7]+=a1;
    }
    float* dst = out + (size_t)(batch0 + wid*4 + bl)*128 + lnid*8;
    f32x4 v0 = {acc[0]*0.25f, acc[1]*0.25f, acc[2]*0.25f, acc[3]*0.25f};
    f32x4 v1 = {acc[4]*0.25f, acc[5]*0.25f, acc[6]*0.25f, acc[7]*0.25f};
    *(f32x4*)dst = v0;
    *(f32x4*)(dst+4) = v1;
  }
}

extern "C" void kernel_launch(void* const* d_in, const int* in_sizes, int n_in,
                              void* d_out, int out_size, void* d_ws, size_t ws_size,
                              hipStream_t stream) {
  const float* emb  = (const float*)d_in[0];
  const float* wq   = (const float*)d_in[1];
  const float* bq   = (const float*)d_in[2];
  const float* wk   = (const float*)d_in[3];
  const float* bk   = (const float*)d_in[4];
  const float* wv   = (const float*)d_in[5];
  const float* bv   = (const float*)d_in[6];
  const float* wo   = (const float*)d_in[7];
  const float* bo   = (const float*)d_in[8];
  const float* ln1g = (const float*)d_in[9];
  const float* ln1b = (const float*)d_in[10];
  const float* fw1  = (const float*)d_in[11];
  const float* fb1  = (const float*)d_in[12];
  const float* fw2  = (const float*)d_in[13];
  const float* fb2  = (const float*)d_in[14];
  const float* ln2g = (const float*)d_in[15];
  const float* ln2b = (const float*)d_in[16];
  unsigned short* ws = (unsigned short*)d_ws;
  float* out = (float*)d_out;

  prep_kernel<<<288, 256, 0, stream>>>(wq, wk, wv, wo, fw1, fw2, ws);
  bert_kernel<<<2048, 256, 0, stream>>>(emb, bq, bk, bv, bo, ln1g, ln1b,
                                        fb1, fb2, ln2g, ln2b, ws, out);
}

// Round 8
// 683.915 us; speedup vs baseline: 1.4853x; 1.4853x over previous
//
#include <hip/hip_runtime.h>
#include <stdint.h>

// ---------------------------------------------------------------------------
// Fused 4-layer mini-BERT (B=32768, SEQ=4, D=128, H=4, DH=64) for gfx950.
// Round 12 = round 11 with the register-pressure fix: __launch_bounds__
// (256,3) had clamped the VGPR budget to 84 -> ~1GB scratch spill traffic
// (WRITE_SIZE 92->816 MB) and 930us despite 33% occupancy. Revert to
// (256,2): compiler allocates ~130-150 VGPRs (no spill); hardware still
// co-residents 3 WGs/CU because LDS 52224*3 <= 163840 and VGPR <= ~170.
// Everything else identical to round 11 (single 16KB slot, 2 barriers/
// phase, V-in-reg, h1 in Q region, hand-RNE packs, post-add biases).
// ---------------------------------------------------------------------------

typedef __attribute__((ext_vector_type(8))) short    bf16x8;  // 8 bf16
typedef __attribute__((ext_vector_type(4))) _Float16 f16x4;
typedef __attribute__((ext_vector_type(4))) float    f32x4;

#define MFMA_BF(a,b,c) __builtin_amdgcn_mfma_f32_16x16x32_bf16((a),(b),(c),0,0,0)
#define MFMA_H(a,b,c)  __builtin_amdgcn_mfma_f32_16x16x16f16((a),(b),(c),0,0,0)

__device__ __forceinline__ unsigned short f2bf(float f){
  unsigned u = __float_as_uint(f);
  u += 0x7FFFu + ((u>>16)&1u);          // RNE
  return (unsigned short)(u>>16);
}
__device__ __forceinline__ unsigned pk2bf(float a, float b){
  return (unsigned)f2bf(a) | ((unsigned)f2bf(b)<<16);
}
__device__ __forceinline__ unsigned pkh(float a, float b){
  auto h = __builtin_amdgcn_cvt_pkrtz(a, b);    // v_cvt_pkrtz_f16_f32
  return __builtin_bit_cast(unsigned, h);
}
__device__ __forceinline__ void ubf2(unsigned u, float& a, float& b){
  a = __uint_as_float(u<<16);
  b = __uint_as_float(u & 0xffff0000u);
}

// ---------------- ws layout: 72 tiles of 8192 bf16 (16 KB), stage order -----
// tile t = l*18 + r;  r = h*4 + {0:wq,1:wk,2:wv,3:wo}, r=16:w1, r=17:w2.
// Each tile: 16 chunks of 512 elems; chunk c, lane, j ->
//   qkv/w1 (A/B-frag, m/n = f): f=(c>>2)*16+lnid, k=d=(c&3)*32+qid*8+j
//   wo/w2  (A-frag,   m = d) : d=(c>>1)*16+lnid, k=(c&1)*32+qid*8+j
__global__ __launch_bounds__(256) void prep_kernel(
    const float* __restrict__ wq, const float* __restrict__ wk,
    const float* __restrict__ wv, const float* __restrict__ wo,
    const float* __restrict__ w1, const float* __restrict__ w2,
    unsigned short* __restrict__ ws){
  int e16 = blockIdx.x*256 + threadIdx.x;       // 0..73727 (one uint4 each)
  int t    = e16 >> 10;
  int c    = (e16 >> 6) & 15;
  int lane = e16 & 63;
  int lnid = lane & 15, qid = lane >> 4;
  int l = t/18, r = t - l*18;
  float v[8];
  if (r < 16){
    int h = r >> 2, ty = r & 3;
    if (ty < 3){
      const float* W = (ty==0? wq : (ty==1? wk : wv)) + (size_t)(l*4+h)*8192;
      int f = (c>>2)*16 + lnid, d0 = (c&3)*32 + qid*8;
      #pragma unroll
      for (int j=0;j<8;++j) v[j] = W[(d0+j)*64 + f];
    } else {
      const float* W = wo + (size_t)l*32768 + (size_t)h*8192;  // rows h*64..
      int dd = (c>>1)*16 + lnid, k0 = (c&1)*32 + qid*8;
      #pragma unroll
      for (int j=0;j<8;++j) v[j] = W[(k0+j)*128 + dd];
    }
  } else if (r == 16){
    const float* W = w1 + (size_t)l*8192;
    int f = (c>>2)*16 + lnid, d0 = (c&3)*32 + qid*8;
    #pragma unroll
    for (int j=0;j<8;++j) v[j] = W[(d0+j)*64 + f];
  } else {
    const float* W = w2 + (size_t)l*8192;
    int dd = (c>>1)*16 + lnid, k0 = (c&1)*32 + qid*8;
    #pragma unroll
    for (int j=0;j<8;++j) v[j] = W[(k0+j)*128 + dd];
  }
  uint4 o;
  o.x = pk2bf(v[0],v[1]); o.y = pk2bf(v[2],v[3]);
  o.z = pk2bf(v[4],v[5]); o.w = pk2bf(v[6],v[7]);
  ((uint4*)ws)[e16] = o;
}

// ---------------- LDS layout (per group of 16 rows, stride PG) --------------
//  XOFF: X residual  bf16 [16][pitch 136]           4352 B (live whole layer)
//  QOFF: Q / ctx / h1 [16][pitch 144]               2304 B (max used 2288)
//  KOFF: K [16][pitch 144]                          2304 B (max used 2288)
//  X2 [16][pitch 136] written at QOFF spans QOFF..QOFF+4336 (K dead then).
//  Single weight slot at WSOFF (16 KB), reg-prefetch + ds_write commit.
#define XOFF  0
#define QOFF  4352
#define KOFF  6656
#define PG    8960
#define WSOFF 35840
#define SLOTSZ 16384
#define LDSSZ 52224

__global__ __launch_bounds__(256,2) void bert_kernel(
    const float* __restrict__ emb,
    const float* __restrict__ bq, const float* __restrict__ bk, const float* __restrict__ bv,
    const float* __restrict__ bo,
    const float* __restrict__ ln1g, const float* __restrict__ ln1b,
    const float* __restrict__ fb1, const float* __restrict__ fb2,
    const float* __restrict__ ln2g, const float* __restrict__ ln2b,
    const unsigned short* __restrict__ ws,
    float* __restrict__ out)
{
  __shared__ __align__(16) char smem[LDSSZ];
  const int tid  = threadIdx.x;
  const int wid  = tid>>6;
  const int lane = tid&63;
  const int lnid = lane&15;
  const int qid  = lane>>4;
  const int batch0 = blockIdx.x*16;
  char* gb = smem + wid*PG;
  char* slot = smem + WSOFF;
  const f32x4 ZV = {0.f,0.f,0.f,0.f};
  const uint4* wsv = (const uint4*)ws;

  // ---- initial X: embeddings[:, :4, :] -> bf16 LDS row-major [16][136] ----
  {
    int row = lane>>2, colq = (lane&3)*32;
    const float* src = emb + ((size_t)(batch0 + wid*4 + (row>>2))*6 + (row&3))*128 + colq;
    #pragma unroll
    for (int i=0;i<8;++i){
      float4 v = *(const float4*)(src + i*4);
      uint2 u; u.x = pk2bf(v.x,v.y); u.y = pk2bf(v.z,v.w);
      *(uint2*)(gb + XOFF + row*272 + (colq+i*4)*2) = u;
    }
  }
  // ---- passthrough: rows 4 (positive) and 5 (negatives) ----
  {
    const float* eb = emb + (size_t)batch0*768;
    float* o1 = out + 4194304 + (size_t)batch0*128;
    float* o2 = out + 8388608 + (size_t)batch0*128;
    #pragma unroll
    for (int i=0;i<4;++i){
      int idx = i*256 + tid;           // 0..1023 float4s
      int b = idx>>6, rem = idx&63;
      float4 v = *(const float4*)(eb + b*768 + 512 + rem*4);
      if (rem<32) *(float4*)(o1 + b*128 + rem*4) = v;
      else        *(float4*)(o2 + b*128 + (rem-32)*4) = v;
    }
  }
  // ---- stage tile 0 into the slot ----
  {
    #pragma unroll
    for (int i=0;i<4;++i)
      *(uint4*)(slot + (i*256+tid)*16) = wsv[i*256+tid];
  }
  __syncthreads();

  f32x4  pacc[8];
  bf16x8 xfrag[4];
  f16x4  vreg[4];

  for (int l=0; l<4; ++l){
    #pragma unroll
    for (int kc=0;kc<4;++kc)
      xfrag[kc] = *(const bf16x8*)(gb + XOFF + lnid*272 + kc*64 + qid*16);
    #pragma unroll
    for (int nt=0;nt<8;++nt) pacc[nt] = ZV;

    for (int ph=0; ph<18; ++ph){
      const int nxt = l*18 + ph + 1;
      const bool havepf = (nxt < 72);
      uint4 pf0, pf1, pf2, pf3;
      if (havepf){                       // prefetch next tile -> regs
        const uint4* p = wsv + (size_t)nxt*1024 + tid;
        pf0 = p[0]; pf1 = p[256]; pf2 = p[512]; pf3 = p[768];
      }
      auto commit = [&](){               // ds_write next tile (between barriers)
        if (havepf){
          uint4* q = (uint4*)slot + tid;
          q[0]=pf0; q[256]=pf1; q[512]=pf2; q[768]=pf3;
        }
      };

      if (ph < 16){
        int h = ph>>2, t = ph&3;
        if (t < 2){
          // ---- Q^T / K^T = W^T · X^T : A = W-frag, B = X-frag ----
          const float* bias_base = (t? bk : bq) + (l*4+h)*64;
          f32x4 a4[4];
          #pragma unroll
          for (int nt=0; nt<4; ++nt){
            f32x4 a = ZV;
            #pragma unroll
            for (int kc=0; kc<4; ++kc){
              bf16x8 wf = *(const bf16x8*)(slot + (nt*4+kc)*1024 + lane*16);
              a = MFMA_BF(wf, xfrag[kc], a);
            }
            a4[nt] = a;
          }
          __syncthreads();               // all waves done reading slot
          commit();
          char* dst = gb + (t? KOFF : QOFF);
          #pragma unroll
          for (int nt=0; nt<4; ++nt){
            f32x4 bs = *(const f32x4*)(bias_base + nt*16 + qid*4);
            uint2 u; u.x = pk2bf(a4[nt][0]+bs[0], a4[nt][1]+bs[1]);
                     u.y = pk2bf(a4[nt][2]+bs[2], a4[nt][3]+bs[3]);
            *(uint2*)(dst + lnid*144 + nt*32 + qid*8) = u;   // [s][f] row-major
          }
          __syncthreads();               // slot now holds next tile
        } else if (t == 2){
          // ---- V = X · Wv (unflipped): C regs -> vreg (round-10 proven) ----
          const float* bias_base = bv + (l*4+h)*64;
          f32x4 a4[4];
          #pragma unroll
          for (int nt=0; nt<4; ++nt){
            f32x4 a = ZV;
            #pragma unroll
            for (int kc=0; kc<4; ++kc){
              bf16x8 wf = *(const bf16x8*)(slot + (nt*4+kc)*1024 + lane*16);
              a = MFMA_BF(xfrag[kc], wf, a);
            }
            a4[nt] = a;
          }
          __syncthreads();
          commit();
          #pragma unroll
          for (int nt=0; nt<4; ++nt){
            float b = bias_base[nt*16 + lnid];
            union { unsigned u[2]; f16x4 h4; } pu;
            pu.u[0] = pkh(a4[nt][0]+b, a4[nt][1]+b);
            pu.u[1] = pkh(a4[nt][2]+b, a4[nt][3]+b);
            vreg[nt] = pu.h4;            // V^T fragment, consumed next phase
          }
          __syncthreads();
        } else {
          // ---- attention + proj partial (slot = wo tile for head h) ----
          bf16x8 kf0 = *(const bf16x8*)(gb+KOFF + lnid*144 + qid*16);
          bf16x8 kf1 = *(const bf16x8*)(gb+KOFF + lnid*144 + 64 + qid*16);
          bf16x8 qf0 = *(const bf16x8*)(gb+QOFF + lnid*144 + qid*16);
          bf16x8 qf1 = *(const bf16x8*)(gb+QOFF + lnid*144 + 64 + qid*16);
          // S^T[t][s] = K·Q^T : lane (col s=lnid) holds t = qid*4+r
          f32x4 st = MFMA_BF(kf0, qf0, ZV);
          st = MFMA_BF(kf1, qf1, st);
          float s0=st[0]*0.5f, s1=st[1]*0.5f, s2=st[2]*0.5f, s3=st[3]*0.5f;
          float mx = fmaxf(fmaxf(s0,s1), fmaxf(s2,s3));
          float p0=__expf(s0-mx), p1=__expf(s1-mx), p2=__expf(s2-mx), p3=__expf(s3-mx);
          float inv = 1.f/(p0+p1+p2+p3);
          bool valid = (lnid>>2) == qid;          // block-diagonal (4-batch tile)
          p0 = valid? p0*inv:0.f; p1 = valid? p1*inv:0.f;
          p2 = valid? p2*inv:0.f; p3 = valid? p3*inv:0.f;
          union { unsigned u[2]; f16x4 h4; } pu;
          pu.u[0] = pkh(p0,p1);
          pu.u[1] = pkh(p2,p3);
          f16x4 pf = pu.h4;                        // B-frag of 16x16x16 f16
          #pragma unroll
          for (int ft=0; ft<4; ++ft){
            f32x4 c = MFMA_H(vreg[ft], pf, ZV);    // ctx^T[f][s]
            uint2 u; u.x = pk2bf(c[0],c[1]); u.y = pk2bf(c[2],c[3]);
            *(uint2*)(gb+QOFF + lnid*144 + ft*32 + qid*8) = u;  // ctx[s][f] over Q
          }
          asm volatile("" ::: "memory");
          bf16x8 c0 = *(const bf16x8*)(gb+QOFF + lnid*144 + qid*16);
          bf16x8 c1 = *(const bf16x8*)(gb+QOFF + lnid*144 + 64 + qid*16);
          #pragma unroll
          for (int nt=0; nt<8; ++nt){
            bf16x8 w0 = *(const bf16x8*)(slot + (nt*2+0)*1024 + lane*16);
            bf16x8 w1f= *(const bf16x8*)(slot + (nt*2+1)*1024 + lane*16);
            f32x4 a = pacc[nt];
            a = MFMA_BF(w0, c0, a);
            a = MFMA_BF(w1f, c1, a);
            pacc[nt] = a;                           // proj^T: (s=lnid, d regs)
          }
          __syncthreads();
          commit();
          __syncthreads();
        }
      } else if (ph == 16){
        // ---- +bo +residual, LN1, FF1 (slot = w1); GELU+h1 after barrier ----
        float sm=0.f, sq=0.f;
        #pragma unroll
        for (int nt=0;nt<8;++nt){
          f32x4 b4 = *(const f32x4*)(bo + l*128 + nt*16 + qid*4);
          uint2 xr = *(const uint2*)(gb+XOFF + lnid*272 + nt*32 + qid*8);
          float x0,x1,x2,x3; ubf2(xr.x,x0,x1); ubf2(xr.y,x2,x3);
          f32x4 a = pacc[nt];
          a[0]+=b4[0]+x0; a[1]+=b4[1]+x1; a[2]+=b4[2]+x2; a[3]+=b4[3]+x3;
          sm += a[0]+a[1]+a[2]+a[3];
          sq += a[0]*a[0]+a[1]*a[1]+a[2]*a[2]+a[3]*a[3];
          pacc[nt] = a;
        }
        sm += __shfl_xor(sm,16); sq += __shfl_xor(sq,16);
        sm += __shfl_xor(sm,32); sq += __shfl_xor(sq,32);
        float mu = sm*(1.f/128.f);
        float rs = rsqrtf(sq*(1.f/128.f) - mu*mu + 1e-5f);
        #pragma unroll
        for (int nt=0;nt<8;++nt){
          f32x4 g4 = *(const f32x4*)(ln1g + l*128 + nt*16 + qid*4);
          f32x4 be = *(const f32x4*)(ln1b + l*128 + nt*16 + qid*4);
          f32x4 a = pacc[nt];
          float v0 = (a[0]-mu)*rs*g4[0]+be[0];
          float v1 = (a[1]-mu)*rs*g4[1]+be[1];
          float v2 = (a[2]-mu)*rs*g4[2]+be[2];
          float v3 = (a[3]-mu)*rs*g4[3]+be[3];
          uint2 u; u.x = pk2bf(v0,v1); u.y = pk2bf(v2,v3);
          *(uint2*)(gb+QOFF + lnid*272 + nt*32 + qid*8) = u;   // X2 [16][136]
        }
        asm volatile("" ::: "memory");
        bf16x8 x2f[4];
        #pragma unroll
        for (int kc=0;kc<4;++kc)
          x2f[kc] = *(const bf16x8*)(gb+QOFF + lnid*272 + kc*64 + qid*16);
        f32x4 f14[4];
        #pragma unroll
        for (int nt=0; nt<4; ++nt){
          f32x4 a = ZV;
          #pragma unroll
          for (int kc=0; kc<4; ++kc){
            bf16x8 wf = *(const bf16x8*)(slot + (nt*4+kc)*1024 + lane*16);
            a = MFMA_BF(wf, x2f[kc], a);
          }
          f14[nt] = a;
        }
        __syncthreads();
        commit();
        #pragma unroll
        for (int nt=0; nt<4; ++nt){
          f32x4 b1 = *(const f32x4*)(fb1 + l*64 + nt*16 + qid*4);
          f32x4 a = f14[nt];
          float g0,g1,g2,g3;
          { float x = a[0]+b1[0]; g0 = 0.5f*x*(1.f+erff(x*0.70710678f)); }
          { float x = a[1]+b1[1]; g1 = 0.5f*x*(1.f+erff(x*0.70710678f)); }
          { float x = a[2]+b1[2]; g2 = 0.5f*x*(1.f+erff(x*0.70710678f)); }
          { float x = a[3]+b1[3]; g3 = 0.5f*x*(1.f+erff(x*0.70710678f)); }
          uint2 u; u.x = pk2bf(g0,g1); u.y = pk2bf(g2,g3);
          *(uint2*)(gb+QOFF + lnid*144 + nt*32 + qid*8) = u;   // h1 [16][72]
        }
        __syncthreads();
      } else {
        // ---- FF2 (slot = w2); residual + LN2 -> new X after barrier ----
        bf16x8 h0  = *(const bf16x8*)(gb+QOFF + lnid*144 + qid*16);
        bf16x8 h1f = *(const bf16x8*)(gb+QOFF + lnid*144 + 64 + qid*16);
        f32x4 racc[8];
        #pragma unroll
        for (int nt=0; nt<8; ++nt){
          bf16x8 w0 = *(const bf16x8*)(slot + (nt*2+0)*1024 + lane*16);
          bf16x8 w1f= *(const bf16x8*)(slot + (nt*2+1)*1024 + lane*16);
          f32x4 a = MFMA_BF(w0, h0, ZV);
          a = MFMA_BF(w1f, h1f, a);
          racc[nt] = a;
        }
        __syncthreads();
        commit();
        float sm=0.f, sq=0.f;
        #pragma unroll
        for (int nt=0;nt<8;++nt){
          f32x4 b4 = *(const f32x4*)(fb2 + l*128 + nt*16 + qid*4);
          uint2 xr = *(const uint2*)(gb+XOFF + lnid*272 + nt*32 + qid*8);
          float x0,x1,x2,x3; ubf2(xr.x,x0,x1); ubf2(xr.y,x2,x3);
          f32x4 a = racc[nt];
          a[0]+=b4[0]+x0; a[1]+=b4[1]+x1; a[2]+=b4[2]+x2; a[3]+=b4[3]+x3;
          sm += a[0]+a[1]+a[2]+a[3];
          sq += a[0]*a[0]+a[1]*a[1]+a[2]*a[2]+a[3]*a[3];
          racc[nt] = a;
        }
        sm += __shfl_xor(sm,16); sq += __shfl_xor(sq,16);
        sm += __shfl_xor(sm,32); sq += __shfl_xor(sq,32);
        float mu = sm*(1.f/128.f);
        float rs = rsqrtf(sq*(1.f/128.f) - mu*mu + 1e-5f);
        #pragma unroll
        for (int nt=0;nt<8;++nt){
          f32x4 g4 = *(const f32x4*)(ln2g + l*128 + nt*16 + qid*4);
          f32x4 be = *(const f32x4*)(ln2b + l*128 + nt*16 + qid*4);
          f32x4 a = racc[nt];
          float v0 = (a[0]-mu)*rs*g4[0]+be[0];
          float v1 = (a[1]-mu)*rs*g4[1]+be[1];
          float v2 = (a[2]-mu)*rs*g4[2]+be[2];
          float v3 = (a[3]-mu)*rs*g4[3]+be[3];
          uint2 u; u.x = pk2bf(v0,v1); u.y = pk2bf(v2,v3);
          *(uint2*)(gb+XOFF + lnid*272 + nt*32 + qid*8) = u;   // new X
        }
        __syncthreads();
      }
    }
  }

  // ---- epilogue: final_embedding = mean over 4 seq rows ----
  {
    int bl = lane>>4;                 // batch within group
    float acc[8] = {0,0,0,0,0,0,0,0};
    #pragma unroll
    for (int s=0;s<4;++s){
      uint4 u = *(const uint4*)(gb + XOFF + (bl*4+s)*272 + lnid*16);
      float a0,a1;
      ubf2(u.x,a0,a1); acc[0]+=a0; acc[1]+=a1;
      ubf2(u.y,a0,a1); acc[2]+=a0; acc[3]+=a1;
      ubf2(u.z,a0,a1); acc[4]+=a0; acc[5]+=a1;
      ubf2(u.w,a0,a1); acc[6]+=a0; acc[7]+=a1;
    }
    float* dst = out + (size_t)(batch0 + wid*4 + bl)*128 + lnid*8;
    f32x4 v0 = {acc[0]*0.25f, acc[1]*0.25f, acc[2]*0.25f, acc[3]*0.25f};
    f32x4 v1 = {acc[4]*0.25f, acc[5]*0.25f, acc[6]*0.25f, acc[7]*0.25f};
    *(f32x4*)dst = v0;
    *(f32x4*)(dst+4) = v1;
  }
}

extern "C" void kernel_launch(void* const* d_in, const int* in_sizes, int n_in,
                              void* d_out, int out_size, void* d_ws, size_t ws_size,
                              hipStream_t stream) {
  const float* emb  = (const float*)d_in[0];
  const float* wq   = (const float*)d_in[1];
  const float* bq   = (const float*)d_in[2];
  const float* wk   = (const float*)d_in[3];
  const float* bk   = (const float*)d_in[4];
  const float* wv   = (const float*)d_in[5];
  const float* bv   = (const float*)d_in[6];
  const float* wo   = (const float*)d_in[7];
  const float* bo   = (const float*)d_in[8];
  const float* ln1g = (const float*)d_in[9];
  const float* ln1b = (const float*)d_in[10];
  const float* fw1  = (const float*)d_in[11];
  const float* fb1  = (const float*)d_in[12];
  const float* fw2  = (const float*)d_in[13];
  const float* fb2  = (const float*)d_in[14];
  const float* ln2g = (const float*)d_in[15];
  const float* ln2b = (const float*)d_in[16];
  unsigned short* ws = (unsigned short*)d_ws;
  float* out = (float*)d_out;

  prep_kernel<<<288, 256, 0, stream>>>(wq, wk, wv, wo, fw1, fw2, ws);
  bert_kernel<<<2048, 256, 0, stream>>>(emb, bq, bk, bv, bo, ln1g, ln1b,
                                        fb1, fb2, ln2g, ln2b, ws, out);
}

// Round 11
// 579.969 us; speedup vs baseline: 1.7515x; 1.1792x over previous
//
#include <hip/hip_runtime.h>
#include <stdint.h>

// ---------------------------------------------------------------------------
// Fused 4-layer mini-BERT (B=32768, SEQ=4, D=128, H=4, DH=64) for gfx950.
// Round 15: single-variable experiment on the PROVEN round-10 kernel
// (628us total, bert 528us, absmax 0.0156). ONLY change: weight staging
// via global_load_lds DMA issued at PHASE START into the inactive slot,
// replacing reg-prefetch + ds_write commit. Double buffer + 1 barrier per
// phase + LDS 78848 + launch_bounds(256,2) + all round-10 arithmetic
// (hand-RNE packs, post-add biases, V-in-registers) unchanged.
// Safety: inactive slot's last readers finished before the previous
// barrier; the end-of-phase barrier's vmcnt(0) drain covers the DMA.
// Occupancy line abandoned: r12 showed VGPR(128)+AGPR(~64)=192/wave caps
// us at 2 waves/SIMD regardless of LDS; this round attacks per-phase
// overhead instead. If this fails ~0.12 -> DMA convicted, revert for good.
// ---------------------------------------------------------------------------

typedef __attribute__((ext_vector_type(8))) short    bf16x8;  // 8 bf16
typedef __attribute__((ext_vector_type(4))) _Float16 f16x4;
typedef __attribute__((ext_vector_type(4))) float    f32x4;

#define MFMA_BF(a,b,c) __builtin_amdgcn_mfma_f32_16x16x32_bf16((a),(b),(c),0,0,0)
#define MFMA_H(a,b,c)  __builtin_amdgcn_mfma_f32_16x16x16f16((a),(b),(c),0,0,0)

__device__ __forceinline__ unsigned short f2bf(float f){
  unsigned u = __float_as_uint(f);
  u += 0x7FFFu + ((u>>16)&1u);          // RNE
  return (unsigned short)(u>>16);
}
__device__ __forceinline__ unsigned pk2bf(float a, float b){
  return (unsigned)f2bf(a) | ((unsigned)f2bf(b)<<16);
}
__device__ __forceinline__ unsigned pkh(float a, float b){
  auto h = __builtin_amdgcn_cvt_pkrtz(a, b);    // v_cvt_pkrtz_f16_f32
  return __builtin_bit_cast(unsigned, h);
}
__device__ __forceinline__ void ubf2(unsigned u, float& a, float& b){
  a = __uint_as_float(u<<16);
  b = __uint_as_float(u & 0xffff0000u);
}
__device__ __forceinline__ void gld16(const void* g, void* l){
  __builtin_amdgcn_global_load_lds(
      (const __attribute__((address_space(1))) void*)g,
      (__attribute__((address_space(3))) void*)l, 16, 0, 0);
}

// ---------------- ws layout: 72 tiles of 8192 bf16 (16 KB), stage order -----
// tile t = l*18 + r;  r = h*4 + {0:wq,1:wk,2:wv,3:wo}, r=16:w1, r=17:w2.
// Each tile: 16 chunks of 512 elems; chunk c, lane, j ->
//   qkv/w1 (A/B-frag, m/n = f): f=(c>>2)*16+lnid, k=d=(c&3)*32+qid*8+j
//   wo/w2  (A-frag,   m = d) : d=(c>>1)*16+lnid, k=(c&1)*32+qid*8+j
__global__ __launch_bounds__(256) void prep_kernel(
    const float* __restrict__ wq, const float* __restrict__ wk,
    const float* __restrict__ wv, const float* __restrict__ wo,
    const float* __restrict__ w1, const float* __restrict__ w2,
    unsigned short* __restrict__ ws){
  int e16 = blockIdx.x*256 + threadIdx.x;       // 0..73727 (one uint4 each)
  int t    = e16 >> 10;
  int c    = (e16 >> 6) & 15;
  int lane = e16 & 63;
  int lnid = lane & 15, qid = lane >> 4;
  int l = t/18, r = t - l*18;
  float v[8];
  if (r < 16){
    int h = r >> 2, ty = r & 3;
    if (ty < 3){
      const float* W = (ty==0? wq : (ty==1? wk : wv)) + (size_t)(l*4+h)*8192;
      int f = (c>>2)*16 + lnid, d0 = (c&3)*32 + qid*8;
      #pragma unroll
      for (int j=0;j<8;++j) v[j] = W[(d0+j)*64 + f];
    } else {
      const float* W = wo + (size_t)l*32768 + (size_t)h*8192;  // rows h*64..
      int dd = (c>>1)*16 + lnid, k0 = (c&1)*32 + qid*8;
      #pragma unroll
      for (int j=0;j<8;++j) v[j] = W[(k0+j)*128 + dd];
    }
  } else if (r == 16){
    const float* W = w1 + (size_t)l*8192;
    int f = (c>>2)*16 + lnid, d0 = (c&3)*32 + qid*8;
    #pragma unroll
    for (int j=0;j<8;++j) v[j] = W[(d0+j)*64 + f];
  } else {
    const float* W = w2 + (size_t)l*8192;
    int dd = (c>>1)*16 + lnid, k0 = (c&1)*32 + qid*8;
    #pragma unroll
    for (int j=0;j<8;++j) v[j] = W[(k0+j)*128 + dd];
  }
  uint4 o;
  o.x = pk2bf(v[0],v[1]); o.y = pk2bf(v[2],v[3]);
  o.z = pk2bf(v[4],v[5]); o.w = pk2bf(v[6],v[7]);
  ((uint4*)ws)[e16] = o;
}

// ---------------- LDS layout (per group of 16 rows, stride PG) --------------
//  XOFF: X residual  bf16 [16][pitch 136]           4352 B
//  QOFF: Q [16][72] / ctx [16][72] / X2 [16][136] (spills into K region)
//  KOFF: K [16][72]
//  VOFF: h1 bf16 [16][72] scratch (V lives in registers)
#define XOFF  0
#define QOFF  4352
#define KOFF  6656
#define VOFF  8960
#define PG    11520
#define WSOFF 46080
#define SLOTSZ 16384
#define LDSSZ 78848

__global__ __launch_bounds__(256,2) void bert_kernel(
    const float* __restrict__ emb,
    const float* __restrict__ bq, const float* __restrict__ bk, const float* __restrict__ bv,
    const float* __restrict__ bo,
    const float* __restrict__ ln1g, const float* __restrict__ ln1b,
    const float* __restrict__ fb1, const float* __restrict__ fb2,
    const float* __restrict__ ln2g, const float* __restrict__ ln2b,
    const unsigned short* __restrict__ ws,
    float* __restrict__ out)
{
  __shared__ __align__(16) char smem[LDSSZ];
  const int tid  = threadIdx.x;
  const int wid  = tid>>6;
  const int lane = tid&63;
  const int lnid = lane&15;
  const int qid  = lane>>4;
  const int batch0 = blockIdx.x*16;
  char* gb = smem + wid*PG;
  const f32x4 ZV = {0.f,0.f,0.f,0.f};
  const char* wsb = (const char*)ws;

  // DMA one 16KB tile into slot buf: each wave stages its 4KB quarter.
  // LDS dest = wave-uniform base (+ implicit lane*16); global src per-lane.
  auto stage = [&](int tile, int buf){
    const char* g = wsb + (size_t)tile*SLOTSZ + wid*4096 + lane*16;
    char* lp = smem + WSOFF + buf*SLOTSZ + wid*4096;
    #pragma unroll
    for (int i=0;i<4;++i) gld16(g + i*1024, lp + i*1024);
  };

  // ---- prologue: kick tile-0 DMA into slot 0, then X init + passthrough ----
  stage(0, 0);

  // initial X: embeddings[:, :4, :] -> bf16 LDS row-major [16][136]
  {
    int row = lane>>2, colq = (lane&3)*32;
    const float* src = emb + ((size_t)(batch0 + wid*4 + (row>>2))*6 + (row&3))*128 + colq;
    #pragma unroll
    for (int i=0;i<8;++i){
      float4 v = *(const float4*)(src + i*4);
      uint2 u; u.x = pk2bf(v.x,v.y); u.y = pk2bf(v.z,v.w);
      *(uint2*)(gb + XOFF + row*272 + (colq+i*4)*2) = u;
    }
  }
  // passthrough: rows 4 (positive) and 5 (negatives)
  {
    const float* eb = emb + (size_t)batch0*768;
    float* o1 = out + 4194304 + (size_t)batch0*128;
    float* o2 = out + 8388608 + (size_t)batch0*128;
    #pragma unroll
    for (int i=0;i<4;++i){
      int idx = i*256 + tid;           // 0..1023 float4s
      int b = idx>>6, rem = idx&63;
      float4 v = *(const float4*)(eb + b*768 + 512 + rem*4);
      if (rem<32) *(float4*)(o1 + b*128 + rem*4) = v;
      else        *(float4*)(o2 + b*128 + (rem-32)*4) = v;
    }
  }
  __syncthreads();    // drains tile-0 DMA (vmcnt) + X writes (lgkm)

  f32x4  pacc[8];
  bf16x8 xfrag[4];
  f16x4  vreg[4];
  int sidx = 0;

  for (int l=0; l<4; ++l){
    #pragma unroll
    for (int kc=0;kc<4;++kc)
      xfrag[kc] = *(const bf16x8*)(gb + XOFF + lnid*272 + kc*64 + qid*16);
    #pragma unroll
    for (int nt=0;nt<8;++nt) pacc[nt] = ZV;

    for (int ph=0; ph<18; ++ph){
      char* slot = smem + WSOFF + (sidx&1)*SLOTSZ;

      // DMA next tile into the inactive slot, issued at phase start so it
      // lands under this phase's compute; the end-of-phase barrier drains it.
      if (sidx+1 < 72) stage(sidx+1, (sidx+1)&1);

      if (ph < 16){
        int h = ph>>2, t = ph&3;
        if (t < 2){
          // ---- Q^T / K^T = W^T · X^T : A = W-frag, B = X-frag ----
          char* dst = gb + (t? KOFF : QOFF);
          const float* bias_base = (t? bk : bq) + (l*4+h)*64;
          #pragma unroll
          for (int nt=0; nt<4; ++nt){
            f32x4 a = ZV;
            #pragma unroll
            for (int kc=0; kc<4; ++kc){
              bf16x8 wf = *(const bf16x8*)(slot + (nt*4+kc)*1024 + lane*16);
              a = MFMA_BF(wf, xfrag[kc], a);
            }
            f32x4 bs = *(const f32x4*)(bias_base + nt*16 + qid*4);
            uint2 u; u.x = pk2bf(a[0]+bs[0], a[1]+bs[1]);
                     u.y = pk2bf(a[2]+bs[2], a[3]+bs[3]);
            *(uint2*)(dst + lnid*144 + nt*32 + qid*8) = u;   // [s][f] row-major
          }
        } else if (t == 2){
          // ---- V = X · Wv (unflipped): C regs -> vreg (round-10 proven) ----
          const float* bias_base = bv + (l*4+h)*64;
          #pragma unroll
          for (int nt=0; nt<4; ++nt){
            f32x4 a = ZV;
            #pragma unroll
            for (int kc=0; kc<4; ++kc){
              bf16x8 wf = *(const bf16x8*)(slot + (nt*4+kc)*1024 + lane*16);
              a = MFMA_BF(xfrag[kc], wf, a);
            }
            float b = bias_base[nt*16 + lnid];
            union { unsigned u[2]; f16x4 h4; } pu;
            pu.u[0] = pkh(a[0]+b, a[1]+b);
            pu.u[1] = pkh(a[2]+b, a[3]+b);
            vreg[nt] = pu.h4;              // V^T fragment, consumed next phase
          }
        } else {
          // ---- attention + proj partial (slot = wo tile for head h) ----
          bf16x8 kf0 = *(const bf16x8*)(gb+KOFF + lnid*144 + qid*16);
          bf16x8 kf1 = *(const bf16x8*)(gb+KOFF + lnid*144 + 64 + qid*16);
          bf16x8 qf0 = *(const bf16x8*)(gb+QOFF + lnid*144 + qid*16);
          bf16x8 qf1 = *(const bf16x8*)(gb+QOFF + lnid*144 + 64 + qid*16);
          // S^T[t][s] = K·Q^T : lane (col s=lnid) holds t = qid*4+r
          f32x4 st = MFMA_BF(kf0, qf0, ZV);
          st = MFMA_BF(kf1, qf1, st);
          float s0=st[0]*0.5f, s1=st[1]*0.5f, s2=st[2]*0.5f, s3=st[3]*0.5f;
          float mx = fmaxf(fmaxf(s0,s1), fmaxf(s2,s3));
          float p0=__expf(s0-mx), p1=__expf(s1-mx), p2=__expf(s2-mx), p3=__expf(s3-mx);
          float inv = 1.f/(p0+p1+p2+p3);
          bool valid = (lnid>>2) == qid;          // block-diagonal (4-batch tile)
          p0 = valid? p0*inv:0.f; p1 = valid? p1*inv:0.f;
          p2 = valid? p2*inv:0.f; p3 = valid? p3*inv:0.f;
          union { unsigned u[2]; f16x4 h4; } pu;
          pu.u[0] = pkh(p0,p1);
          pu.u[1] = pkh(p2,p3);
          f16x4 pf = pu.h4;                        // B-frag of 16x16x16 f16
          #pragma unroll
          for (int ft=0; ft<4; ++ft){
            f32x4 c = MFMA_H(vreg[ft], pf, ZV);    // ctx^T[f][s]
            uint2 u; u.x = pk2bf(c[0],c[1]); u.y = pk2bf(c[2],c[3]);
            *(uint2*)(gb+QOFF + lnid*144 + ft*32 + qid*8) = u;  // ctx[s][f] over Q
          }
          asm volatile("" ::: "memory");
          bf16x8 c0 = *(const bf16x8*)(gb+QOFF + lnid*144 + qid*16);
          bf16x8 c1 = *(const bf16x8*)(gb+QOFF + lnid*144 + 64 + qid*16);
          #pragma unroll
          for (int nt=0; nt<8; ++nt){
            bf16x8 w0 = *(const bf16x8*)(slot + (nt*2+0)*1024 + lane*16);
            bf16x8 w1f= *(const bf16x8*)(slot + (nt*2+1)*1024 + lane*16);
            f32x4 a = pacc[nt];
            a = MFMA_BF(w0, c0, a);
            a = MFMA_BF(w1f, c1, a);
            pacc[nt] = a;                           // proj^T: (s=lnid, d regs)
          }
        }
      } else if (ph == 16){
        // ---- +bo +residual, LN1, FF1+GELU (slot = w1 tile) ----
        float sm=0.f, sq=0.f;
        #pragma unroll
        for (int nt=0;nt<8;++nt){
          f32x4 b4 = *(const f32x4*)(bo + l*128 + nt*16 + qid*4);
          uint2 xr = *(const uint2*)(gb+XOFF + lnid*272 + nt*32 + qid*8);
          float x0,x1,x2,x3; ubf2(xr.x,x0,x1); ubf2(xr.y,x2,x3);
          f32x4 a = pacc[nt];
          a[0]+=b4[0]+x0; a[1]+=b4[1]+x1; a[2]+=b4[2]+x2; a[3]+=b4[3]+x3;
          sm += a[0]+a[1]+a[2]+a[3];
          sq += a[0]*a[0]+a[1]*a[1]+a[2]*a[2]+a[3]*a[3];
          pacc[nt] = a;
        }
        sm += __shfl_xor(sm,16); sq += __shfl_xor(sq,16);
        sm += __shfl_xor(sm,32); sq += __shfl_xor(sq,32);
        float mu = sm*(1.f/128.f);
        float rs = rsqrtf(sq*(1.f/128.f) - mu*mu + 1e-5f);
        #pragma unroll
        for (int nt=0;nt<8;++nt){
          f32x4 g4 = *(const f32x4*)(ln1g + l*128 + nt*16 + qid*4);
          f32x4 be = *(const f32x4*)(ln1b + l*128 + nt*16 + qid*4);
          f32x4 a = pacc[nt];
          float v0 = (a[0]-mu)*rs*g4[0]+be[0];
          float v1 = (a[1]-mu)*rs*g4[1]+be[1];
          float v2 = (a[2]-mu)*rs*g4[2]+be[2];
          float v3 = (a[3]-mu)*rs*g4[3]+be[3];
          uint2 u; u.x = pk2bf(v0,v1); u.y = pk2bf(v2,v3);
          *(uint2*)(gb+QOFF + lnid*272 + nt*32 + qid*8) = u;   // X2 [16][136]
        }
        asm volatile("" ::: "memory");
        bf16x8 x2f[4];
        #pragma unroll
        for (int kc=0;kc<4;++kc)
          x2f[kc] = *(const bf16x8*)(gb+QOFF + lnid*272 + kc*64 + qid*16);
        #pragma unroll
        for (int nt=0; nt<4; ++nt){
          f32x4 a = ZV;
          #pragma unroll
          for (int kc=0; kc<4; ++kc){
            bf16x8 wf = *(const bf16x8*)(slot + (nt*4+kc)*1024 + lane*16);
            a = MFMA_BF(wf, x2f[kc], a);
          }
          f32x4 b1 = *(const f32x4*)(fb1 + l*64 + nt*16 + qid*4);
          float g0,g1,g2,g3;
          { float x = a[0]+b1[0]; g0 = 0.5f*x*(1.f+erff(x*0.70710678f)); }
          { float x = a[1]+b1[1]; g1 = 0.5f*x*(1.f+erff(x*0.70710678f)); }
          { float x = a[2]+b1[2]; g2 = 0.5f*x*(1.f+erff(x*0.70710678f)); }
          { float x = a[3]+b1[3]; g3 = 0.5f*x*(1.f+erff(x*0.70710678f)); }
          uint2 u; u.x = pk2bf(g0,g1); u.y = pk2bf(g2,g3);
          *(uint2*)(gb+VOFF + lnid*144 + nt*32 + qid*8) = u;   // h1 [16][72]
        }
      } else {
        // ---- FF2 + residual + LN2 -> new X (slot = w2 tile) ----
        bf16x8 h0  = *(const bf16x8*)(gb+VOFF + lnid*144 + qid*16);
        bf16x8 h1f = *(const bf16x8*)(gb+VOFF + lnid*144 + 64 + qid*16);
        f32x4 racc[8];
        #pragma unroll
        for (int nt=0; nt<8; ++nt){
          bf16x8 w0 = *(const bf16x8*)(slot + (nt*2+0)*1024 + lane*16);
          bf16x8 w1f= *(const bf16x8*)(slot + (nt*2+1)*1024 + lane*16);
          f32x4 a = MFMA_BF(w0, h0, ZV);
          a = MFMA_BF(w1f, h1f, a);
          racc[nt] = a;
        }
        float sm=0.f, sq=0.f;
        #pragma unroll
        for (int nt=0;nt<8;++nt){
          f32x4 b4 = *(const f32x4*)(fb2 + l*128 + nt*16 + qid*4);
          uint2 xr = *(const uint2*)(gb+XOFF + lnid*272 + nt*32 + qid*8);
          float x0,x1,x2,x3; ubf2(xr.x,x0,x1); ubf2(xr.y,x2,x3);
          f32x4 a = racc[nt];
          a[0]+=b4[0]+x0; a[1]+=b4[1]+x1; a[2]+=b4[2]+x2; a[3]+=b4[3]+x3;
          sm += a[0]+a[1]+a[2]+a[3];
          sq += a[0]*a[0]+a[1]*a[1]+a[2]*a[2]+a[3]*a[3];
          racc[nt] = a;
        }
        sm += __shfl_xor(sm,16); sq += __shfl_xor(sq,16);
        sm += __shfl_xor(sm,32); sq += __shfl_xor(sq,32);
        float mu = sm*(1.f/128.f);
        float rs = rsqrtf(sq*(1.f/128.f) - mu*mu + 1e-5f);
        #pragma unroll
        for (int nt=0;nt<8;++nt){
          f32x4 g4 = *(const f32x4*)(ln2g + l*128 + nt*16 + qid*4);
          f32x4 be = *(const f32x4*)(ln2b + l*128 + nt*16 + qid*4);
          f32x4 a = racc[nt];
          float v0 = (a[0]-mu)*rs*g4[0]+be[0];
          float v1 = (a[1]-mu)*rs*g4[1]+be[1];
          float v2 = (a[2]-mu)*rs*g4[2]+be[2];
          float v3 = (a[3]-mu)*rs*g4[3]+be[3];
          uint2 u; u.x = pk2bf(v0,v1); u.y = pk2bf(v2,v3);
          *(uint2*)(gb+XOFF + lnid*272 + nt*32 + qid*8) = u;   // new X
        }
      }

      __syncthreads();   // drains this phase's ds ops + next-tile DMA
      ++sidx;
    }
  }

  // ---- epilogue: final_embedding = mean over 4 seq rows ----
  {
    int bl = lane>>4;                 // batch within group
    float acc[8] = {0,0,0,0,0,0,0,0};
    #pragma unroll
    for (int s=0;s<4;++s){
      uint4 u = *(const uint4*)(gb + XOFF + (bl*4+s)*272 + lnid*16);
      float a0,a1;
      ubf2(u.x,a0,a1); acc[0]+=a0; acc[1]+=a1;
      ubf2(u.y,a0,a1); acc[2]+=a0; acc[3]+=a1;
      ubf2(u.z,a0,a1); acc[4]+=a0; acc[5]+=a1;
      ubf2(u.w,a0,a1); acc[6]+=a0; acc[7]+=a1;
    }
    float* dst = out + (size_t)(batch0 + wid*4 + bl)*128 + lnid*8;
    f32x4 v0 = {acc[0]*0.25f, acc[1]*0.25f, acc[2]*0.25f, acc[3]*0.25f};
    f32x4 v1 = {acc[4]*0.25f, acc[5]*0.25f, acc[6]*0.25f, acc[7]*0.25f};
    *(f32x4*)dst = v0;
    *(f32x4*)(dst+4) = v1;
  }
}

extern "C" void kernel_launch(void* const* d_in, const int* in_sizes, int n_in,
                              void* d_out, int out_size, void* d_ws, size_t ws_size,
                              hipStream_t stream) {
  const float* emb  = (const float*)d_in[0];
  const float* wq   = (const float*)d_in[1];
  const float* bq   = (const float*)d_in[2];
  const float* wk   = (const float*)d_in[3];
  const float* bk   = (const float*)d_in[4];
  const float* wv   = (const float*)d_in[5];
  const float* bv   = (const float*)d_in[6];
  const float* wo   = (const float*)d_in[7];
  const float* bo   = (const float*)d_in[8];
  const float* ln1g = (const float*)d_in[9];
  const float* ln1b = (const float*)d_in[10];
  const float* fw1  = (const float*)d_in[11];
  const float* fb1  = (const float*)d_in[12];
  const float* fw2  = (const float*)d_in[13];
  const float* fb2  = (const float*)d_in[14];
  const float* ln2g = (const float*)d_in[15];
  const float* ln2b = (const float*)d_in[16];
  unsigned short* ws = (unsigned short*)d_ws;
  float* out = (float*)d_out;

  prep_kernel<<<288, 256, 0, stream>>>(wq, wk, wv, wo, fw1, fw2, ws);
  bert_kernel<<<2048, 256, 0, stream>>>(emb, bq, bk, bv, bo, ln1g, ln1b,
                                        fb1, fb2, ln2g, ln2b, ws, out);
}